// Round 4
// baseline (957.296 us; speedup 1.0000x reference)
//
#include <hip/hip_runtime.h>
#include <hip/hip_bf16.h>
#include <stdint.h>

// Problem constants (fixed by the reference)
#define NE      1048576     // edges
#define NNODES  65536       // B*N
#define DIMV    64          // embedding dim
#define HDIM    256         // SwiGLU hidden width

typedef __bf16 bf16x8 __attribute__((ext_vector_type(8)));
typedef float  f32x4  __attribute__((ext_vector_type(4)));

__device__ __forceinline__ unsigned short f2bf(float f) {
    union { float f; uint32_t u; } v; v.f = f;
    return (unsigned short)((v.u + 0x7fffu + ((v.u >> 16) & 1u)) >> 16);  // RNE
}

// ---------------- prep 1: node features fp32 -> bf16 table ----------------
__global__ void prep_x_kernel(const float* __restrict__ x, unsigned short* __restrict__ xb) {
    int i = blockIdx.x * blockDim.x + threadIdx.x;
    const int total = NNODES * DIMV / 4;
    for (; i < total; i += gridDim.x * blockDim.x) {
        float4 v = ((const float4*)x)[i];
        ushort4 o;
        o.x = f2bf(v.x); o.y = f2bf(v.y); o.z = f2bf(v.z); o.w = f2bf(v.w);
        ((ushort4*)xb)[i] = o;
    }
}

// ------- prep 2: weights -> transposed, XOR-swizzled bf16 LDS images -------
// Per matrix 65536 B: column h (0..255), 16B chunk cc (0..15) holding W[k][h]
// for k = cc*8..cc*8+7, at byte h*256 + ((cc*16) ^ ((h&7)<<4)).
// w_out is folded into Wi: wi'[k][h] = wi[k][h] * wo[h].
__global__ void prep_w_kernel(const float* __restrict__ wg, const float* __restrict__ wi,
                              const float* __restrict__ wo, unsigned short* __restrict__ img) {
    int t = blockIdx.x * blockDim.x + threadIdx.x;
    if (t >= 2 * HDIM * 16) return;
    int mat = t >> 12;
    int h   = (t >> 4) & 255;
    int cc  = t & 15;
    const float* w = mat ? wi : wg;
    float scale = mat ? wo[h] : 1.0f;
    unsigned short tmp[8] __attribute__((aligned(16)));
    #pragma unroll
    for (int j = 0; j < 8; ++j)
        tmp[j] = f2bf(w[(cc * 8 + j) * HDIM + h] * scale);
    int byteoff = mat * 65536 + h * 256 + ((cc * 16) ^ ((h & 7) << 4));
    *(uint4*)((char*)img + byteoff) = *(const uint4*)tmp;
}

// ---------------- main: fused gather + dual GEMM + SwiGLU + reduce ----------------
// 512 threads (8 waves), M_REP=8 -> 128 edges/wave, 1024 edges/block, grid=NE/1024.
// Full Wg+Wi' (bf16, transposed, swizzled) resident in 128 KiB LDS.
// LDS caps occupancy at 1 WG/CU = 2 waves/EU no matter what, so ask the allocator
// for the min=1 waves/EU budget (up to 512 VGPRs) -- peak live here is ~239.
#define M_REP 8
#define EDGES_PER_BLOCK (8 * 16 * M_REP)   // 1024
__global__ __attribute__((amdgpu_flat_work_group_size(512, 512), amdgpu_waves_per_eu(1, 8)))
void edge_swiglu_kernel(
    const unsigned short* __restrict__ xb,
    const unsigned short* __restrict__ wimg,
    const int* __restrict__ eidx,
    float* __restrict__ out)
{
    __shared__ char wlds[131072];

    const int tid  = threadIdx.x;
    const int lane = tid & 63;
    const int wave = tid >> 6;
    const int r = lane & 15;       // A row (edge) / B col (h) selector
    const int q = lane >> 4;       // k-group selector

    const int eb = blockIdx.x * EDGES_PER_BLOCK + wave * (16 * M_REP);

    // gather A fragments first (32 independent 16B loads; latency hides under staging)
    // A-frag layout (16x16x32): row = lane&15, k = (lane>>4)*8 + j
    bf16x8 a[M_REP][4];
    #pragma unroll
    for (int m = 0; m < M_REP; ++m) {
        int e  = eb + m * 16 + r;
        int sc = eidx[e];
        int gl = eidx[NE + e];
        #pragma unroll
        for (int ks = 0; ks < 4; ++ks) {
            int node = (ks < 2) ? sc : gl;                 // k<64 -> scope, else goal
            const unsigned short* p = xb + node * DIMV + (ks & 1) * 32 + q * 8;
            a[m][ks] = *(const bf16x8*)p;
        }
    }

    // stage pre-swizzled weight images -> LDS (linear b128 copy)
    {
        const uint4* src = (const uint4*)wimg;
        uint4* dst = (uint4*)wlds;
        #pragma unroll
        for (int i = 0; i < 16; ++i) {
            int idx = tid + i * 512;
            dst[idx] = src[idx];
        }
    }

    float part[M_REP][4];
    #pragma unroll
    for (int m = 0; m < M_REP; ++m)
        #pragma unroll
        for (int j = 0; j < 4; ++j) part[m][j] = 0.0f;

    __syncthreads();

    const int rbase = (r << 8);            // h*256 = (nf*16+r)*256 -> nf*4096 + rbase
    const int swz   = (r & 7) << 4;        // h&7 == r&7

    #pragma unroll
    for (int nf = 0; nf < 16; ++nf) {
        const int rowoff = nf * 4096 + rbase;
        const f32x4 zero = {0.0f, 0.0f, 0.0f, 0.0f};

        // load all 8 B-fragments for this nf once, reuse across all m
        bf16x8 bg[4], bi[4];
        #pragma unroll
        for (int ks = 0; ks < 4; ++ks) {
            int cb = (ks * 64 + q * 16) ^ swz;
            bg[ks] = *(const bf16x8*)(wlds + rowoff + cb);
            bi[ks] = *(const bf16x8*)(wlds + 65536 + rowoff + cb);
        }

        // two half-batches of 4 edges-frags: 8 independent MFMA chains each,
        // epilogue right after -> only 32 acc regs live at a time
        #pragma unroll
        for (int mh = 0; mh < 2; ++mh) {
            f32x4 accG[4], accI[4];
            #pragma unroll
            for (int mi = 0; mi < 4; ++mi) { accG[mi] = zero; accI[mi] = zero; }
            #pragma unroll
            for (int ks = 0; ks < 4; ++ks) {
                #pragma unroll
                for (int mi = 0; mi < 4; ++mi) {
                    const int m = mh * 4 + mi;
                    accG[mi] = __builtin_amdgcn_mfma_f32_16x16x32_bf16(a[m][ks], bg[ks], accG[mi], 0, 0, 0);
                    accI[mi] = __builtin_amdgcn_mfma_f32_16x16x32_bf16(a[m][ks], bi[ks], accI[mi], 0, 0, 0);
                }
            }
            #pragma unroll
            for (int mi = 0; mi < 4; ++mi) {
                const int m = mh * 4 + mi;
                #pragma unroll
                for (int j = 0; j < 4; ++j) {
                    float g  = accG[mi][j];
                    float iv = accI[mi][j];
                    float e  = __builtin_amdgcn_exp2f(g * -1.44269504f);
                    float s  = __builtin_amdgcn_rcpf(1.0f + e);
                    part[m][j] = __builtin_fmaf(g * s, iv, part[m][j]);
                }
            }
        }
    }

    // reduce over h (16 low lanes), store 4 edges per (q,m): D row = q*4+j
    #pragma unroll
    for (int m = 0; m < M_REP; ++m) {
        f32x4 v;
        #pragma unroll
        for (int j = 0; j < 4; ++j) {
            float s = part[m][j];
            s += __shfl_xor(s, 1);
            s += __shfl_xor(s, 2);
            s += __shfl_xor(s, 4);
            s += __shfl_xor(s, 8);
            v[j] = s;
        }
        if (r == 0)
            *(f32x4*)(out + eb + m * 16 + q * 4) = v;
    }
}

extern "C" void kernel_launch(void* const* d_in, const int* in_sizes, int n_in,
                              void* d_out, int out_size, void* d_ws, size_t ws_size,
                              hipStream_t stream) {
    const float* x   = (const float*)d_in[0];   // [65536, 64] fp32
    const float* wg  = (const float*)d_in[1];   // [128, 256] fp32
    const float* wi  = (const float*)d_in[2];   // [128, 256] fp32
    const float* wo  = (const float*)d_in[3];   // [256] fp32
    const int*   ei  = (const int*)d_in[4];     // [2, E] int
    float* out = (float*)d_out;

    unsigned short* xb   = (unsigned short*)d_ws;                       // 8 MiB bf16 node table
    unsigned short* wimg = (unsigned short*)((char*)d_ws + 8388608);    // 128 KiB weight images

    prep_x_kernel<<<1024, 256, 0, stream>>>(x, xb);
    prep_w_kernel<<<32, 256, 0, stream>>>(wg, wi, wo, wimg);
    edge_swiglu_kernel<<<NE / EDGES_PER_BLOCK, 512, 0, stream>>>(xb, wimg, ei, out);
}

// Round 5
// 194.777 us; speedup vs baseline: 4.9148x; 4.9148x over previous
//
#include <hip/hip_runtime.h>
#include <hip/hip_bf16.h>
#include <stdint.h>

// Problem constants (fixed by the reference)
#define NE      1048576     // edges
#define NNODES  65536       // B*N
#define DIMV    64          // embedding dim
#define HDIM    256         // SwiGLU hidden width

typedef __bf16 bf16x8 __attribute__((ext_vector_type(8)));
typedef float  f32x4  __attribute__((ext_vector_type(4)));

__device__ __forceinline__ unsigned short f2bf(float f) {
    union { float f; uint32_t u; } v; v.f = f;
    return (unsigned short)((v.u + 0x7fffu + ((v.u >> 16) & 1u)) >> 16);  // RNE
}

// ---------------- prep 1: node features fp32 -> bf16 table ----------------
__global__ void prep_x_kernel(const float* __restrict__ x, unsigned short* __restrict__ xb) {
    int i = blockIdx.x * blockDim.x + threadIdx.x;
    const int total = NNODES * DIMV / 4;
    for (; i < total; i += gridDim.x * blockDim.x) {
        float4 v = ((const float4*)x)[i];
        ushort4 o;
        o.x = f2bf(v.x); o.y = f2bf(v.y); o.z = f2bf(v.z); o.w = f2bf(v.w);
        ((ushort4*)xb)[i] = o;
    }
}

// ------- prep 2: weights -> transposed, XOR-swizzled bf16 LDS images -------
// Per matrix 65536 B: column h (0..255), 16B chunk cc (0..15) holding W[k][h]
// for k = cc*8..cc*8+7, at byte h*256 + ((cc*16) ^ ((h&7)<<4)).
// w_out is folded into Wi: wi'[k][h] = wi[k][h] * wo[h].
__global__ void prep_w_kernel(const float* __restrict__ wg, const float* __restrict__ wi,
                              const float* __restrict__ wo, unsigned short* __restrict__ img) {
    int t = blockIdx.x * blockDim.x + threadIdx.x;
    if (t >= 2 * HDIM * 16) return;
    int mat = t >> 12;
    int h   = (t >> 4) & 255;
    int cc  = t & 15;
    const float* w = mat ? wi : wg;
    float scale = mat ? wo[h] : 1.0f;
    unsigned short tmp[8] __attribute__((aligned(16)));
    #pragma unroll
    for (int j = 0; j < 8; ++j)
        tmp[j] = f2bf(w[(cc * 8 + j) * HDIM + h] * scale);
    int byteoff = mat * 65536 + h * 256 + ((cc * 16) ^ ((h & 7) << 4));
    *(uint4*)((char*)img + byteoff) = *(const uint4*)tmp;
}

// ---------------- main: fused gather + dual GEMM + SwiGLU + reduce ----------------
// 512 threads (8 waves), M_REP=2 -> 32 edges/wave, 256 edges/block, grid=NE/256.
// Full Wg+Wi' (bf16, transposed, swizzled) resident in 128 KiB LDS.
// DESIGN CONSTRAINT (R1-R4 evidence): allocator pegs this kernel at 128 VGPRs no
// matter what attributes we pass; M_REP=2 keeps peak live regs ~100 -> no spills.
#define M_REP 2
#define EDGES_PER_BLOCK (8 * 16 * M_REP)   // 256
__global__ __launch_bounds__(512)
void edge_swiglu_kernel(
    const unsigned short* __restrict__ xb,
    const unsigned short* __restrict__ wimg,
    const int* __restrict__ eidx,
    float* __restrict__ out)
{
    __shared__ char wlds[131072];

    const int tid  = threadIdx.x;
    const int lane = tid & 63;
    const int wave = tid >> 6;
    const int r = lane & 15;       // A row (edge) / B col (h) selector
    const int q = lane >> 4;       // k-group selector

    const int eb = blockIdx.x * EDGES_PER_BLOCK + wave * (16 * M_REP);

    // gather A fragments (8 independent 16B loads; latency hides under staging)
    // A-frag layout (16x16x32): row = lane&15, k = (lane>>4)*8 + j
    bf16x8 a[M_REP][4];
    #pragma unroll
    for (int m = 0; m < M_REP; ++m) {
        int e  = eb + m * 16 + r;
        int sc = eidx[e];
        int gl = eidx[NE + e];
        #pragma unroll
        for (int ks = 0; ks < 4; ++ks) {
            int node = (ks < 2) ? sc : gl;                 // k<64 -> scope, else goal
            const unsigned short* p = xb + node * DIMV + (ks & 1) * 32 + q * 8;
            a[m][ks] = *(const bf16x8*)p;
        }
    }

    // stage pre-swizzled weight images -> LDS (linear b128 copy)
    {
        const uint4* src = (const uint4*)wimg;
        uint4* dst = (uint4*)wlds;
        #pragma unroll
        for (int i = 0; i < 16; ++i) {
            int idx = tid + i * 512;
            dst[idx] = src[idx];
        }
    }

    float part[M_REP][4];
    #pragma unroll
    for (int m = 0; m < M_REP; ++m)
        #pragma unroll
        for (int j = 0; j < 4; ++j) part[m][j] = 0.0f;

    // swizzled within-row byte offsets are nf-invariant: hoist out of the loop
    const int swz = (r & 7) << 4;          // h&7 == r&7
    int cb[4];
    #pragma unroll
    for (int ks = 0; ks < 4; ++ks) cb[ks] = (ks * 64 + q * 16) ^ swz;
    const int rbase = (r << 8);            // h*256 = (nf*16+r)*256 -> nf*4096 + rbase

    __syncthreads();

    #pragma unroll
    for (int nf = 0; nf < 16; ++nf) {
        const int rowoff = nf * 4096 + rbase;
        const f32x4 zero = {0.0f, 0.0f, 0.0f, 0.0f};

        // load all 8 B-fragments for this nf once, reuse across both m
        bf16x8 bg[4], bi[4];
        #pragma unroll
        for (int ks = 0; ks < 4; ++ks) {
            bg[ks] = *(const bf16x8*)(wlds + rowoff + cb[ks]);
            bi[ks] = *(const bf16x8*)(wlds + 65536 + rowoff + cb[ks]);
        }

        // 4 independent 4-deep MFMA chains (2 m x 2 matrices)
        f32x4 accG[M_REP], accI[M_REP];
        #pragma unroll
        for (int m = 0; m < M_REP; ++m) { accG[m] = zero; accI[m] = zero; }
        #pragma unroll
        for (int ks = 0; ks < 4; ++ks) {
            #pragma unroll
            for (int m = 0; m < M_REP; ++m) {
                accG[m] = __builtin_amdgcn_mfma_f32_16x16x32_bf16(a[m][ks], bg[ks], accG[m], 0, 0, 0);
                accI[m] = __builtin_amdgcn_mfma_f32_16x16x32_bf16(a[m][ks], bi[ks], accI[m], 0, 0, 0);
            }
        }

        // part += silu(g) * i'   (wo already folded into Wi')
        #pragma unroll
        for (int m = 0; m < M_REP; ++m) {
            #pragma unroll
            for (int j = 0; j < 4; ++j) {
                float g  = accG[m][j];
                float iv = accI[m][j];
                float e  = __builtin_amdgcn_exp2f(g * -1.44269504f);
                float s  = __builtin_amdgcn_rcpf(1.0f + e);
                part[m][j] = __builtin_fmaf(g * s, iv, part[m][j]);
            }
        }
    }

    // reduce over h (16 low lanes), store 4 edges per (q,m): D row = q*4+j
    #pragma unroll
    for (int m = 0; m < M_REP; ++m) {
        f32x4 v;
        #pragma unroll
        for (int j = 0; j < 4; ++j) {
            float s = part[m][j];
            s += __shfl_xor(s, 1);
            s += __shfl_xor(s, 2);
            s += __shfl_xor(s, 4);
            s += __shfl_xor(s, 8);
            v[j] = s;
        }
        if (r == 0)
            *(f32x4*)(out + eb + m * 16 + q * 4) = v;
    }
}

extern "C" void kernel_launch(void* const* d_in, const int* in_sizes, int n_in,
                              void* d_out, int out_size, void* d_ws, size_t ws_size,
                              hipStream_t stream) {
    const float* x   = (const float*)d_in[0];   // [65536, 64] fp32
    const float* wg  = (const float*)d_in[1];   // [128, 256] fp32
    const float* wi  = (const float*)d_in[2];   // [128, 256] fp32
    const float* wo  = (const float*)d_in[3];   // [256] fp32
    const int*   ei  = (const int*)d_in[4];     // [2, E] int
    float* out = (float*)d_out;

    unsigned short* xb   = (unsigned short*)d_ws;                       // 8 MiB bf16 node table
    unsigned short* wimg = (unsigned short*)((char*)d_ws + 8388608);    // 128 KiB weight images

    prep_x_kernel<<<1024, 256, 0, stream>>>(x, xb);
    prep_w_kernel<<<32, 256, 0, stream>>>(wg, wi, wo, wimg);
    edge_swiglu_kernel<<<NE / EDGES_PER_BLOCK, 512, 0, stream>>>(xb, wimg, ei, out);
}

// Round 6
// 140.873 us; speedup vs baseline: 6.7955x; 1.3826x over previous
//
#include <hip/hip_runtime.h>
#include <hip/hip_bf16.h>
#include <stdint.h>

// Problem constants (fixed by the reference)
#define NE      1048576     // edges
#define NNODES  65536       // B*N
#define DIMV    64          // embedding dim
#define HDIM    256         // SwiGLU hidden width

typedef __bf16 bf16x8 __attribute__((ext_vector_type(8)));
typedef float  f32x4  __attribute__((ext_vector_type(4)));

__device__ __forceinline__ unsigned short f2bf(float f) {
    union { float f; uint32_t u; } v; v.f = f;
    return (unsigned short)((v.u + 0x7fffu + ((v.u >> 16) & 1u)) >> 16);  // RNE
}

// ---------------- prep 1: node features fp32 -> bf16 table ----------------
__global__ void prep_x_kernel(const float* __restrict__ x, unsigned short* __restrict__ xb) {
    int i = blockIdx.x * blockDim.x + threadIdx.x;
    const int total = NNODES * DIMV / 4;
    for (; i < total; i += gridDim.x * blockDim.x) {
        float4 v = ((const float4*)x)[i];
        ushort4 o;
        o.x = f2bf(v.x); o.y = f2bf(v.y); o.z = f2bf(v.z); o.w = f2bf(v.w);
        ((ushort4*)xb)[i] = o;
    }
}

// ------- prep 2: weights -> transposed, XOR-swizzled bf16 images -------
// Per matrix 65536 B: column h (0..255), 16B chunk cc (0..15) holding W[k][h]
// for k = cc*8..cc*8+7, at byte h*256 + ((cc*16) ^ ((h&7)<<4)).
// w_out is folded into Wi: wi'[k][h] = wi[k][h] * wo[h].
__global__ void prep_w_kernel(const float* __restrict__ wg, const float* __restrict__ wi,
                              const float* __restrict__ wo, unsigned short* __restrict__ img) {
    int t = blockIdx.x * blockDim.x + threadIdx.x;
    if (t >= 2 * HDIM * 16) return;
    int mat = t >> 12;
    int h   = (t >> 4) & 255;
    int cc  = t & 15;
    const float* w = mat ? wi : wg;
    float scale = mat ? wo[h] : 1.0f;
    unsigned short tmp[8] __attribute__((aligned(16)));
    #pragma unroll
    for (int j = 0; j < 8; ++j)
        tmp[j] = f2bf(w[(cc * 8 + j) * HDIM + h] * scale);
    int byteoff = mat * 65536 + h * 256 + ((cc * 16) ^ ((h & 7) << 4));
    *(uint4*)((char*)img + byteoff) = *(const uint4*)tmp;
}

// ---------------- main: swapped-operand fused kernel ----------------
// Block = 512 threads (8 waves), 256 edges. Wave w owns h-slice [32w, 32w+32)
// with its W^T fragments resident in 64 VGPRs (loaded once from global).
// Block stages 256 edges x 256B gathered features into 64KB LDS ONCE via
// global_load_lds (linear LDS dest, pre-swizzled per-lane global source);
// all 8 waves share them. D[h,e] layout -> h-reduction is in-lane; cross-wave
// combine via 8KB LDS partial strip. ~105 live VGPRs (hard cap is 128).
#define EDGES_PER_BLOCK 256
__global__ __launch_bounds__(512)
void edge_swiglu_kernel(
    const unsigned short* __restrict__ xb,
    const unsigned short* __restrict__ wimg,
    const int* __restrict__ eidx,
    float* __restrict__ out)
{
    __shared__ char  alds[EDGES_PER_BLOCK * 256];   // 64 KiB gathered features
    __shared__ float plds[8][EDGES_PER_BLOCK];      // 8 KiB per-wave partials

    const int tid  = threadIdx.x;
    const int lane = tid & 63;
    const int wave = tid >> 6;
    const int r = lane & 15;       // A-row (h) / B-col (edge) lane selector
    const int q = lane >> 4;       // k-group selector
    const int eb = blockIdx.x * EDGES_PER_BLOCK;

    // ---- stage gathered edge features -> LDS (issue first; latency hides
    // under the B-register loads below). chunk idx: el = idx>>4, c = idx&15.
    // LDS slot (el, c) holds node-half (c>>3), source chunk (c&7)^(el&7).
    #pragma unroll
    for (int i = 0; i < 8; ++i) {
        int idx  = i * 512 + tid;
        int el   = idx >> 4;
        int c    = idx & 15;
        int half = c >> 3;
        int srcc = (c & 7) ^ (el & 7);
        int e    = eb + el;
        int node = half ? eidx[NE + e] : eidx[e];
        const unsigned short* src = xb + node * 64 + srcc * 8;
        __builtin_amdgcn_global_load_lds(
            (const __attribute__((address_space(1))) void*)src,
            (__attribute__((address_space(3))) void*)(alds + idx * 16),
            16, 0, 0);
    }

    // ---- W^T fragments into registers: wave's 32-h slice (nf = 2*wave+nh)
    // A-operand layout (16x16x32): row = lane&15 = h-within-16, k = q*8+j.
    bf16x8 bw[2][2][4];   // [nh][mat][ks]
    #pragma unroll
    for (int nh = 0; nh < 2; ++nh) {
        int h      = (wave * 2 + nh) * 16 + r;
        int rowoff = h << 8;
        int swz    = (h & 7) << 4;
        #pragma unroll
        for (int mat = 0; mat < 2; ++mat) {
            #pragma unroll
            for (int ks = 0; ks < 4; ++ks) {
                int cb = ((4 * ks + q) * 16) ^ swz;
                bw[nh][mat][ks] = *(const bf16x8*)((const char*)wimg + mat * 65536 + rowoff + cb);
            }
        }
    }

    __syncthreads();   // barrier drains vmcnt -> staged A complete

    // ---- main loop: 16 M-frags of 16 edges
    #pragma unroll 2
    for (int mf = 0; mf < 16; ++mf) {
        const int   el   = mf * 16 + r;
        const char* arow = alds + el * 256;

        // X-frags (B-operand): col = lane&15 = edge, k = q*8+j per ks-tile.
        // chunk ck = 4*ks+q; LDS slot c = (ck&8) | ((ck&7) ^ (r&7)).
        bf16x8 x[4];
        #pragma unroll
        for (int ks = 0; ks < 4; ++ks) {
            int ck = 4 * ks + q;
            int c  = (ck & 8) | ((ck & 7) ^ (r & 7));
            x[ks] = *(const bf16x8*)(arow + c * 16);
        }

        float part = 0.0f;
        #pragma unroll
        for (int nh = 0; nh < 2; ++nh) {
            f32x4 aG = {0.0f, 0.0f, 0.0f, 0.0f};
            f32x4 aI = {0.0f, 0.0f, 0.0f, 0.0f};
            #pragma unroll
            for (int ks = 0; ks < 4; ++ks) {
                aG = __builtin_amdgcn_mfma_f32_16x16x32_bf16(bw[nh][0][ks], x[ks], aG, 0, 0, 0);
                aI = __builtin_amdgcn_mfma_f32_16x16x32_bf16(bw[nh][1][ks], x[ks], aI, 0, 0, 0);
            }
            // D[h,e]: lane holds h = nf*16 + q*4 + j for edge el -> in-lane sum
            #pragma unroll
            for (int j = 0; j < 4; ++j) {
                float g  = aG[j];
                float iv = aI[j];
                float e2 = __builtin_amdgcn_exp2f(g * -1.44269504f);
                float s  = __builtin_amdgcn_rcpf(1.0f + e2);
                part = __builtin_fmaf(g * s, iv, part);
            }
        }
        // sum over q-groups (h-quarters): lanes differing in bits 4,5
        part += __shfl_xor(part, 16);
        part += __shfl_xor(part, 32);
        if (lane < 16) plds[wave][mf * 16 + lane] = part;
    }

    __syncthreads();

    // ---- combine the 8 wave partials per edge, coalesced store
    if (tid < EDGES_PER_BLOCK) {
        float s = 0.0f;
        #pragma unroll
        for (int w = 0; w < 8; ++w) s += plds[w][tid];
        out[eb + tid] = s;
    }
}

extern "C" void kernel_launch(void* const* d_in, const int* in_sizes, int n_in,
                              void* d_out, int out_size, void* d_ws, size_t ws_size,
                              hipStream_t stream) {
    const float* x   = (const float*)d_in[0];   // [65536, 64] fp32
    const float* wg  = (const float*)d_in[1];   // [128, 256] fp32
    const float* wi  = (const float*)d_in[2];   // [128, 256] fp32
    const float* wo  = (const float*)d_in[3];   // [256] fp32
    const int*   ei  = (const int*)d_in[4];     // [2, E] int
    float* out = (float*)d_out;

    unsigned short* xb   = (unsigned short*)d_ws;                       // 8 MiB bf16 node table
    unsigned short* wimg = (unsigned short*)((char*)d_ws + 8388608);    // 128 KiB weight images

    prep_x_kernel<<<1024, 256, 0, stream>>>(x, xb);
    prep_w_kernel<<<32, 256, 0, stream>>>(wg, wi, wo, wimg);
    edge_swiglu_kernel<<<NE / EDGES_PER_BLOCK, 512, 0, stream>>>(xb, wimg, ei, out);
}